// Round 1
// baseline (687.810 us; speedup 1.0000x reference)
//
#include <hip/hip_runtime.h>

#define NN 200000
#define NE 1000000
#define DD 64

__global__ __launch_bounds__(256) void gcn_edge_kernel(
    const int* __restrict__ src, const int* __restrict__ dst,
    const float* __restrict__ review, const float* __restrict__ ci,
    const float* __restrict__ W1, const float* __restrict__ W2,
    const float* __restrict__ f2, const float* __restrict__ f3,
    float* __restrict__ out)
{
    float* out_rst = out;                          // pass 2: (feature2[src] + review@W2^T)
    float* out_re  = out + (size_t)NN * DD;        // pass 1: review@W1^T
    float* out_id  = out + 2 * (size_t)NN * DD;    // pass 3: feature3[src]

    const int lane = threadIdx.x & 63;
    const int waveInBlock = threadIdx.x >> 6;
    const int wavesPerBlock = blockDim.x >> 6;
    const int gwave = blockIdx.x * wavesPerBlock + waveInBlock;
    const int nwaves = gridDim.x * wavesPerBlock;

    // Lane j caches W1 row j and W2 row j in registers (16 KB each, L2-hit).
    float w1[DD], w2[DD];
    const float4* W1v = reinterpret_cast<const float4*>(W1 + lane * DD);
    const float4* W2v = reinterpret_cast<const float4*>(W2 + lane * DD);
#pragma unroll
    for (int q = 0; q < DD / 4; ++q) {
        float4 a = W1v[q];
        float4 b = W2v[q];
        w1[q * 4 + 0] = a.x; w1[q * 4 + 1] = a.y; w1[q * 4 + 2] = a.z; w1[q * 4 + 3] = a.w;
        w2[q * 4 + 0] = b.x; w2[q * 4 + 1] = b.y; w2[q * 4 + 2] = b.z; w2[q * 4 + 3] = b.w;
    }

    for (int e = gwave; e < NE; e += nwaves) {
        const int s = src[e];
        const int d = dst[e];
        const float coef = ci[s] * ci[d];   // fold ci_src * ci_dst into the message

        // lane j computes r1[j] = sum_k review[e][k]*W1[j][k], r2 likewise.
        const float x = review[(size_t)e * DD + lane];
        float acc1 = 0.f, acc2 = 0.f;
#pragma unroll
        for (int k = 0; k < DD; ++k) {
            const float b = __uint_as_float(
                __builtin_amdgcn_readlane(__float_as_uint(x), k));  // wave broadcast via SGPR
            acc1 = fmaf(b, w1[k], acc1);
            acc2 = fmaf(b, w2[k], acc2);
        }

        const float v2 = f2[(size_t)s * DD + lane];
        const float v3 = f3[(size_t)s * DD + lane];

        atomicAdd(&out_rst[(size_t)d * DD + lane], (v2 + acc2) * coef);
        atomicAdd(&out_re [(size_t)d * DD + lane], acc1 * coef);
        atomicAdd(&out_id [(size_t)d * DD + lane], v3 * coef);
    }
}

extern "C" void kernel_launch(void* const* d_in, const int* in_sizes, int n_in,
                              void* d_out, int out_size, void* d_ws, size_t ws_size,
                              hipStream_t stream) {
    const int*   src    = (const int*)d_in[0];
    const int*   dst    = (const int*)d_in[1];
    const float* review = (const float*)d_in[2];
    const float* ci     = (const float*)d_in[3];
    // d_in[4] = feature (unused by the reference computation)
    const float* W1     = (const float*)d_in[5];
    const float* W2     = (const float*)d_in[6];
    const float* f2     = (const float*)d_in[7];
    const float* f3     = (const float*)d_in[8];
    float* out = (float*)d_out;

    // Zero the accumulation target (harness poisons it; no re-poison between replays).
    hipMemsetAsync(out, 0, (size_t)out_size * sizeof(float), stream);

    const int block = 256;   // 4 waves/block
    const int grid  = 2048;  // 8192 waves, ~122 edges each, grid-stride
    gcn_edge_kernel<<<grid, block, 0, stream>>>(src, dst, review, ci, W1, W2, f2, f3, out);
}